// Round 5
// baseline (756.117 us; speedup 1.0000x reference)
//
#include <hip/hip_runtime.h>
#include <math.h>

#define H       2048
#define E       64
#define NCH     64          // chunks of 32 floats across H
#define T_TOK   32768
#define GATES_OFF   0
#define IDX_OFF     65536
#define LOSS_OFF    131072

// ---- zero the 128-float accumulator ----
__global__ void zero_accum_kernel(float* __restrict__ accum) {
    accum[threadIdx.x] = 0.f;    // 128 threads
}

__device__ __forceinline__ void async_copy16(const float* g, void* l) {
    __builtin_amdgcn_global_load_lds(
        (const __attribute__((address_space(1))) unsigned int*)g,
        (__attribute__((address_space(3))) unsigned int*)l,
        16, 0, 0);
}

// ---------------- main gating kernel ----------------
// lane = token (64 tokens/block); wave w owns experts [8w, 8w+8) -> acc[8] only
// (spill-proof; round-1/2 showed acc[64] forces scratch).
// x staged per 32-float chunk into LDS via global_load_lds: linear LDS dest,
// quad-permuted global source, XOR-swizzled read (m173/m201 involution pattern;
// kills the stride-128B 32-way bank conflict). k-order of the FMA chain is
// bitwise-identical to the round-0 passing kernel (ascending k, fmaf).
// W read directly from the host-uploaded input with plain vector loads
// (wave-uniform addresses) -- no workspace-written data on any scalar path.
__global__ __launch_bounds__(512, 4) void gate_main_kernel(
        const float* __restrict__ x,         // (T, H) fp32
        const float* __restrict__ W,         // (E, H) fp32, row-major
        float* __restrict__ out,
        float* __restrict__ accum)           // [0:64) sum probs, [64:128) counts
{
    __shared__ float xs[2][2048];            // 2 x 8 KB x-chunk double buffer
    __shared__ float lg[64][68];             // logits -> probs (pad 4)
    __shared__ float ct[64][68];             // (p>0) counts

    const int tid  = threadIdx.x;
    const int lane = tid & 63;
    const int wv   = tid >> 6;
    const int wvu  = __builtin_amdgcn_readfirstlane(wv);
    const int tokBase = blockIdx.x * 64;
    const float* xg = x + (size_t)tokBase * H;

    // staging: thread tid fills LDS 16B slot tid (linear dest = uniform+lane*16).
    // slot holds token t=tid>>3, physical quad p=tid&7 = logical quad p^(t&7).
    const int s_tok = tid >> 3;
    const int s_q   = (tid & 7) ^ (s_tok & 7);
    const float* s_src = xg + (size_t)s_tok * H + s_q * 4;
    auto stage = [&](int c) {
        async_copy16(s_src + c * 32, &xs[c & 1][tid * 4]);
    };

    float acc[8];
#pragma unroll
    for (int e2 = 0; e2 < 8; ++e2) acc[e2] = 0.f;

    stage(0);
    __syncthreads();

    const int   lsw   = lane & 7;
    const float* xrow0 = &xs[0][lane * 32];
    const float* wrow  = W + (size_t)(wvu * 8) * H;   // this wave's 8 experts

    for (int c = 0; c < NCH; ++c) {
        if (c + 1 < NCH) stage(c + 1);       // ~900cy HBM latency under ~2000cy FMA

        // this lane's token row, logical quads 0..7 (XOR involution read)
        const float* xrow = xrow0 + (c & 1) * 2048;
        float4 xq0 = *(const float4*)&xrow[((0 ^ lsw)) * 4];
        float4 xq1 = *(const float4*)&xrow[((1 ^ lsw)) * 4];
        float4 xq2 = *(const float4*)&xrow[((2 ^ lsw)) * 4];
        float4 xq3 = *(const float4*)&xrow[((3 ^ lsw)) * 4];
        float4 xq4 = *(const float4*)&xrow[((4 ^ lsw)) * 4];
        float4 xq5 = *(const float4*)&xrow[((5 ^ lsw)) * 4];
        float4 xq6 = *(const float4*)&xrow[((6 ^ lsw)) * 4];
        float4 xq7 = *(const float4*)&xrow[((7 ^ lsw)) * 4];

#pragma unroll
        for (int e2 = 0; e2 < 8; ++e2) {
            const float4* wp = (const float4*)(wrow + (size_t)e2 * H + c * 32);
            float4 w0 = wp[0], w1 = wp[1], w2 = wp[2], w3 = wp[3];
            float4 w4 = wp[4], w5 = wp[5], w6 = wp[6], w7 = wp[7];
            float a = acc[e2];
            a = fmaf(xq0.x, w0.x, a); a = fmaf(xq0.y, w0.y, a);
            a = fmaf(xq0.z, w0.z, a); a = fmaf(xq0.w, w0.w, a);
            a = fmaf(xq1.x, w1.x, a); a = fmaf(xq1.y, w1.y, a);
            a = fmaf(xq1.z, w1.z, a); a = fmaf(xq1.w, w1.w, a);
            a = fmaf(xq2.x, w2.x, a); a = fmaf(xq2.y, w2.y, a);
            a = fmaf(xq2.z, w2.z, a); a = fmaf(xq2.w, w2.w, a);
            a = fmaf(xq3.x, w3.x, a); a = fmaf(xq3.y, w3.y, a);
            a = fmaf(xq3.z, w3.z, a); a = fmaf(xq3.w, w3.w, a);
            a = fmaf(xq4.x, w4.x, a); a = fmaf(xq4.y, w4.y, a);
            a = fmaf(xq4.z, w4.z, a); a = fmaf(xq4.w, w4.w, a);
            a = fmaf(xq5.x, w5.x, a); a = fmaf(xq5.y, w5.y, a);
            a = fmaf(xq5.z, w5.z, a); a = fmaf(xq5.w, w5.w, a);
            a = fmaf(xq6.x, w6.x, a); a = fmaf(xq6.y, w6.y, a);
            a = fmaf(xq6.z, w6.z, a); a = fmaf(xq6.w, w6.w, a);
            a = fmaf(xq7.x, w7.x, a); a = fmaf(xq7.y, w7.y, a);
            a = fmaf(xq7.z, w7.z, a); a = fmaf(xq7.w, w7.w, a);
            acc[e2] = a;
        }
        __syncthreads();   // drains stage(c+1) vmcnt + releases xs[c&1]
    }

    // ---- gather logits per token: lg[tok][expert] ----
    *(float4*)&lg[lane][wv * 8]     = make_float4(acc[0], acc[1], acc[2], acc[3]);
    *(float4*)&lg[lane][wv * 8 + 4] = make_float4(acc[4], acc[5], acc[6], acc[7]);
    __syncthreads();

    // ---- epilogue: wave 0, lane = token, full 64-expert row in registers ----
    if (wv == 0) {
        float l[64];
#pragma unroll
        for (int i = 0; i < 16; ++i)
            *(float4*)&l[i * 4] = *(const float4*)&lg[lane][i * 4];

        // top-2, strict > keeps lower index on ties (matches lax.top_k)
        float v1 = l[0]; int i1 = 0;
        float v2 = -INFINITY; int i2 = 0;
#pragma unroll
        for (int e = 1; e < E; ++e) {
            float v = l[e];
            if (v > v1)      { v2 = v1; i2 = i1; v1 = v; i1 = e; }
            else if (v > v2) { v2 = v;  i2 = e; }
        }

        // softmax over 64 experts (v1 is the max)
        float s = 0.f;
#pragma unroll
        for (int e = 0; e < E; ++e) { l[e] = __expf(l[e] - v1); s += l[e]; }
        float inv = 1.f / s;

        // stage p and (p>0) rows for the per-expert reduce
#pragma unroll
        for (int i = 0; i < 16; ++i) {
            float p0 = l[i*4]   * inv;
            float p1 = l[i*4+1] * inv;
            float p2 = l[i*4+2] * inv;
            float p3 = l[i*4+3] * inv;
            *(float4*)&lg[lane][i * 4] = make_float4(p0, p1, p2, p3);
            *(float4*)&ct[lane][i * 4] = make_float4(p0 > 0.f ? 1.f : 0.f,
                                                     p1 > 0.f ? 1.f : 0.f,
                                                     p2 > 0.f ? 1.f : 0.f,
                                                     p3 > 0.f ? 1.f : 0.f);
        }

        int token = tokBase + lane;
        float t = __expf(v2 - v1);
        float d = 1.f / (1.f + t);
        *(float2*)&out[GATES_OFF + 2 * token] = make_float2(d, t * d);
        *(float2*)&out[IDX_OFF   + 2 * token] = make_float2((float)i1, (float)i2);
    }
    __syncthreads();

    // ---- per-expert partial sums: lane = expert, wave covers 8 tokens ----
    {
        float sp = 0.f, sc = 0.f;
#pragma unroll
        for (int t0 = 0; t0 < 8; ++t0) {
            int t = wv * 8 + t0;
            sp += lg[t][lane];               // bank (4t+lane)%32: conflict-free
            sc += ct[t][lane];
        }
        atomicAdd(&accum[lane],     sp);
        atomicAdd(&accum[E + lane], sc);
    }
}

// ---------------- final loss kernel ----------------
__global__ void gate_final_kernel(const float* __restrict__ accum, float* __restrict__ out) {
    int lane = threadIdx.x;                  // 64 threads
    const float invT = 1.f / (float)T_TOK;
    float mean_p  = accum[lane] * invT;
    float routing = accum[E + lane] * invT;
    float term = mean_p * routing;
#pragma unroll
    for (int d = 32; d > 0; d >>= 1) term += __shfl_xor(term, d, 64);
    if (lane == 0) out[LOSS_OFF] = 64.f * term;
}

extern "C" void kernel_launch(void* const* d_in, const int* in_sizes, int n_in,
                              void* d_out, int out_size, void* d_ws, size_t ws_size,
                              hipStream_t stream) {
    const float* x = (const float*)d_in[0];   // (4,8192,2048) fp32
    const float* W = (const float*)d_in[1];   // (64,2048) fp32
    float* out   = (float*)d_out;
    float* accum = (float*)d_ws;              // 128 floats

    zero_accum_kernel<<<1, 128, 0, stream>>>(accum);
    gate_main_kernel<<<T_TOK / 64, 512, 0, stream>>>(x, W, out, accum);
    gate_final_kernel<<<1, 64, 0, stream>>>(accum, out);
}